// Round 15
// baseline (66.872 us; speedup 1.0000x reference)
//
#include <hip/hip_runtime.h>

#define B_ 4
#define C_ 128
#define H_ 128
#define W_ 256
#define HW_ (H_ * W_)
#define ND 81
#define TH 8          // output rows per block
#define TW 16         // output cols per block
#define HR 16         // f2 halo rows  (TH + 8)
#define WCOL 32       // f2 halo cols
#define KC 32         // channels per LDS chunk (= MFMA K)
#define NCHUNK (C_ / KC)
#define NTHREADS 512

typedef short bf16x8 __attribute__((ext_vector_type(8)));
typedef float f32x4 __attribute__((ext_vector_type(4)));
typedef float f32x4v __attribute__((ext_vector_type(4)));
typedef unsigned int u32x4 __attribute__((ext_vector_type(4)));

// Swizzle (HW-verified R1/R3-R14): XOR bits 4..6 of the full byte address by
// (r & 7) << 4 where r = px>>1 lives in bits >=7. Bijective. MFMA reads:
// dy (+32 px) and t (+16 px) keep (r&7) -> single vaddr + imm offsets.
__device__ __forceinline__ int swz(int px, int byteInHalf) {
    int r = px >> 1;
    int base = (r << 7) + ((px & 1) << 6) + byteInHalf;
    return base ^ ((r & 7) << 4);
}

__device__ __forceinline__ unsigned int cvt_pk_bf16(float a, float b) {
    unsigned int r;
    asm("v_cvt_pk_bf16_f32 %0, %1, %2" : "=v"(r) : "v"(a), "v"(b));
    return r;
}

// ss += lo(u)^2 + hi(u)^2, one VOP3P instruction (R10-verified).
__device__ __forceinline__ void dot2_sq(unsigned int u, float& ss) {
    asm("v_dot2_f32_bf16 %0, %1, %1, %0" : "+v"(ss) : "v"(u));
}

// Barrier WITHOUT vmcnt drain (R6-verified): LDS ordered, globals in flight.
#define BARRIER()                                             \
    do {                                                      \
        asm volatile("s_waitcnt lgkmcnt(0)" ::: "memory");    \
        __builtin_amdgcn_s_barrier();                         \
    } while (0)

__global__ __launch_bounds__(NTHREADS)
void corr81_kernel(const float* __restrict__ f1g, const float* __restrict__ f2g,
                   float* __restrict__ out) {
    // R15 residency probe: SINGLE-buffered staging, 43.5 KB total -> 2 (or 3)
    // blocks/CU guaranteed co-resident even with driver LDS reservation.
    // Cost: 2 barriers/chunk (write->bar->read->bar) instead of 1.
    __shared__ __align__(16) unsigned short f2s[HR * WCOL * KC];  // 32 KB
    __shared__ __align__(16) unsigned short f1s[TH * TW * KC];    // 8 KB
    __shared__ float invn2[HR * WCOL];                            // 2 KB
    __shared__ float invn1[TH * TW];                              // 0.5 KB

    const int tid  = threadIdx.x;
    const int lane = tid & 63;
    const int wave = tid >> 6;            // 0..7 -> output row within tile
    const int col  = lane & 15;
    const int quad = lane >> 4;

    // XCD-aware block swizzle (T1, verified R4). Bijective: 1024 = 8*128.
    const int flat = blockIdx.x + 16 * blockIdx.y + 256 * blockIdx.z;
    const int orig = (flat & 7) * 128 + (flat >> 3);
    const int w0 = (orig & 15) * TW;
    const int h0 = ((orig >> 4) & 15) * TH;
    const int b  = orig >> 8;
    const size_t inBase = (size_t)b * C_ * HW_;
    const float* f2base = f2g + inBase;
    const float* f1base = f1g + inBase;

    // f2 staging: (i 0..3) x per-thread (g2, cp2, rq)
    const int g2  = tid & 7;
    const int cp2 = (tid >> 3) & 15;
    const int rq  = tid >> 7;
    const int gw2 = w0 - 4 + g2 * 4;
    const bool colok2 = (gw2 >= 0) && (gw2 < W_);

    // f1 staging: one float4-pair per thread
    const int g1  = tid & 3;
    const int cp1 = (tid >> 2) & 15;
    const int r1  = tid >> 6;

    // chunk-invariant 32-bit offsets (R14-verified): base advances on SALU.
    bool vrow[4];
    int off2[4];
#pragma unroll
    for (int i = 0; i < 4; ++i) {
        int r  = i * 4 + rq;
        int gh = h0 - 4 + r;
        vrow[i] = colok2 && (gh >= 0) && (gh < H_);
        off2[i] = cp2 * 2 * HW_ + (vrow[i] ? (gh * W_ + gw2) : 0);
    }
    const int off1 = cp1 * 2 * HW_ + (h0 + r1) * W_ + (w0 + g1 * 4);

    // MFMA fragment bases (single vaddr + imm offsets, R14-verified).
    const int rb2 = swz(wave * 32 + col, quad * 16);
    const int rb1 = swz(wave * 16 + col, quad * 16);
    const char* f2c = (const char*)&f2s[0];
    const char* f1c = (const char*)&f1s[0];

    f32x4 acc[9][2];
#pragma unroll
    for (int d = 0; d < 9; ++d) {
        acc[d][0] = (f32x4)0.f;
        acc[d][1] = (f32x4)0.f;
    }

    float ss2 = 0.f, ss1 = 0.f;
    // prefetch regs: zero ONCE; invalid lanes never overwritten after.
    f32x4v A0[4] = {}, A1[4] = {}, B0, B1;

#define ISSUE_LOADS(kc0)                                                        \
    {                                                                           \
        const float* bk2 = f2base + (size_t)(kc0) * HW_;                        \
        const float* bk1 = f1base + (size_t)(kc0) * HW_;                        \
        _Pragma("unroll")                                                       \
        for (int i = 0; i < 4; ++i) {                                           \
            if (vrow[i]) {                                                      \
                A0[i] = *(const f32x4v*)(bk2 + off2[i]);                        \
                A1[i] = *(const f32x4v*)(bk2 + off2[i] + HW_);                  \
            }                                                                   \
        }                                                                       \
        B0 = *(const f32x4v*)(bk1 + off1);                                      \
        B1 = *(const f32x4v*)(bk1 + off1 + HW_);                                \
    }

#define PACK_WRITE()                                                            \
    {                                                                           \
        char* w2 = (char*)&f2s[0];                                              \
        char* w1 = (char*)&f1s[0];                                              \
        _Pragma("unroll")                                                       \
        for (int i = 0; i < 4; ++i) {                                           \
            int r = i * 4 + rq;                                                 \
            _Pragma("unroll")                                                   \
            for (int j = 0; j < 4; ++j) {                                       \
                int px = r * 32 + g2 * 4 + j;                                   \
                *(unsigned int*)(w2 + swz(px, cp2 * 4)) =                       \
                    cvt_pk_bf16(A0[i][j], A1[i][j]);                            \
            }                                                                   \
        }                                                                       \
        _Pragma("unroll")                                                       \
        for (int j = 0; j < 4; ++j) {                                           \
            int px = r1 * 16 + g1 * 4 + j;                                      \
            *(unsigned int*)(w1 + swz(px, cp1 * 4)) = cvt_pk_bf16(B0[j], B1[j]);\
        }                                                                       \
    }

#define MFMA_PHASE()                                                            \
    {                                                                           \
        bf16x8 af = *(const bf16x8*)(f1c + rb1);                                \
        _Pragma("unroll")                                                       \
        for (int dy = 0; dy < 9; ++dy) {                                        \
            bf16x8 b0 = *(const bf16x8*)(f2c + rb2 + dy * 2048);                \
            bf16x8 b1 = *(const bf16x8*)(f2c + rb2 + dy * 2048 + 1024);         \
            acc[dy][0] = __builtin_amdgcn_mfma_f32_16x16x32_bf16(af, b0, acc[dy][0], 0, 0, 0); \
            acc[dy][1] = __builtin_amdgcn_mfma_f32_16x16x32_bf16(af, b1, acc[dy][1], 0, 0, 0); \
        }                                                                       \
    }

#define NORM_PHASE()                                                            \
    {                                                                           \
        _Pragma("unroll")                                                       \
        for (int j = 0; j < 4; ++j) {                                           \
            u32x4 v = *(const u32x4*)(f2c + swz(tid, j * 16));                  \
            dot2_sq(v[0], ss2); dot2_sq(v[1], ss2);                             \
            dot2_sq(v[2], ss2); dot2_sq(v[3], ss2);                             \
        }                                                                       \
        u32x4 v = *(const u32x4*)(f1c + swz(tid >> 2, (tid & 3) * 16));         \
        dot2_sq(v[0], ss1); dot2_sq(v[1], ss1);                                 \
        dot2_sq(v[2], ss1); dot2_sq(v[3], ss1);                                 \
    }

    // ---- prologue: stage chunk 0, issue chunk-1 loads ----
    ISSUE_LOADS(0);
    PACK_WRITE();
    ISSUE_LOADS(KC);
    BARRIER();

    // ---- main: single buffer, write->bar->read->bar ----
#pragma unroll
    for (int k = 0; k < NCHUNK; ++k) {
        MFMA_PHASE();
        NORM_PHASE();
        if (k == NCHUNK - 1) {
            invn2[tid] = 1.f / fmaxf(sqrtf(ss2), 1e-12f);
            float t1 = ss1 + __shfl_xor(ss1, 1);
            t1 += __shfl_xor(t1, 2);
            if ((tid & 3) == 0) invn1[tid >> 2] = 1.f / fmaxf(sqrtf(t1), 1e-12f);
        }
        BARRIER();                       // chunk-k reads complete (+ invn visible at k=3)
        if (k < NCHUNK - 1) {
            PACK_WRITE();                // stage chunk k+1 (regs from iter k-1)
            if (k < NCHUNK - 2) ISSUE_LOADS((k + 2) * KC);
            BARRIER();                   // chunk-(k+1) writes complete
        }
    }

    // ---- epilogue: extract band, rescale, leaky-relu, store ----
    const int hOut = h0 + wave;
    float* outB = out + (size_t)b * ND * HW_ + (size_t)hOut * W_;
    const float scale = 1.f / (float)C_;

#pragma unroll
    for (int dy = 0; dy < 9; ++dy) {
        int hr = wave + dy;
#pragma unroll
        for (int t = 0; t < 2; ++t) {
            float i2 = invn2[hr * WCOL + t * 16 + col];
#pragma unroll
            for (int r = 0; r < 4; ++r) {
                int row = quad * 4 + r;
                int dx = t * 16 + col - row;
                if (dx >= 0 && dx <= 8) {
                    float v = acc[dy][t][r] * invn1[wave * 16 + row] * i2 * scale;
                    v = (v >= 0.f) ? v : 0.1f * v;
                    outB[(size_t)(dy * 9 + dx) * HW_ + (w0 + row)] = v;
                }
            }
        }
    }
#undef ISSUE_LOADS
#undef PACK_WRITE
#undef MFMA_PHASE
#undef NORM_PHASE
}

extern "C" void kernel_launch(void* const* d_in, const int* in_sizes, int n_in,
                              void* d_out, int out_size, void* d_ws, size_t ws_size,
                              hipStream_t stream) {
    const float* f1 = (const float*)d_in[0];
    const float* f2 = (const float*)d_in[1];
    float* out = (float*)d_out;
    dim3 grid(W_ / TW, H_ / TH, B_);   // 16 x 16 x 4 = 1024 blocks
    corr81_kernel<<<grid, NTHREADS, 0, stream>>>(f1, f2, out);
}